// Round 10
// baseline (754.011 us; speedup 1.0000x reference)
//
#include <hip/hip_runtime.h>
#include <hip/hip_bf16.h>

// ---------------------------------------------------------------------------
// DGLRGCN on MI355X. Round 14: R11 (737us, known-good) with ONE delta --
// the L0 GEMM switches BM128xBN128 -> BM64xBN128 (same fragment-major
// gload_lds body, BM/BN-parameterized): grid 782 -> 1564 blocks, LDS
// 36 -> ~26 KB -> ~5-6 blocks/CU (was ~3). Inter-block overlap is the only
// mechanism that ever absorbed the barrier-drain stalls (R5 3/CU=115us vs
// R8 2/CU=131us). R12/R13's prep/count2 merge is DROPPED (two infra
// failures on that source; isolate the variable). Front-end kernels are
// byte-identical to R11.
// ---------------------------------------------------------------------------

#define HD   256
#define EPS  1e-5f
#define NREL 5
#define ND0  50000
#define ND1  10000
#define BK   64

typedef unsigned short ushort_t;
using f32x4  = __attribute__((ext_vector_type(4))) float;
using short8 = __attribute__((ext_vector_type(8))) short;

__device__ __forceinline__ ushort_t f2b(float f) {
    union { float f; unsigned u; } x; x.f = f;
    unsigned r = x.u + 0x7FFF + ((x.u >> 16) & 1);   // RNE
    return (ushort_t)(r >> 16);
}
__device__ __forceinline__ float b2f(ushort_t h) {
    union { unsigned u; float f; } x; x.u = ((unsigned)h) << 16;
    return x.f;
}

// global(16B) -> LDS DMA, one wave-instruction covers 1024B (64 lanes x 16B)
#define GLOAD_LDS16(gp, lp)                                                     \
    __builtin_amdgcn_global_load_lds(                                           \
        (const __attribute__((address_space(1))) unsigned int*)(gp),            \
        (__attribute__((address_space(3))) unsigned int*)(lp), 16, 0, 0)

// ---------------- prep: weights conv + x conv + zeroing (one kernel) -------
struct WconvArgs {
    const float* src[14];
    ushort_t*    dst[14];
    int          N[14];
};
// sections: [0,3584) wconv | [3584,53584) xconv | [53584,53877) cnt | [53877] st
__global__ void prep_kernel(WconvArgs a, const float* __restrict__ x,
                            ushort_t* __restrict__ xb, int n4,
                            int* __restrict__ cnt, int ncnt4,
                            float* __restrict__ st) {
    int b = blockIdx.x;
    int tid = threadIdx.x;
    if (b < 3584) {
        int mat = b >> 8;
        int id = (b & 255) * 256 + tid;     // 0..65535
        int n = id >> 8, k = id & 255;
        int N = a.N[mat];
        float v = (n < N) ? a.src[mat][(size_t)k * N + n] : 0.f;
        a.dst[mat][id] = f2b(v);
    } else if (b < 53584) {
        int id = (b - 3584) * 256 + tid;
        if (id < n4) {
            float4 v = ((const float4*)x)[id];
            ushort4 o; o.x = f2b(v.x); o.y = f2b(v.y); o.z = f2b(v.z); o.w = f2b(v.w);
            ((ushort4*)xb)[id] = o;
        }
    } else if (b < 53877) {
        int id = (b - 53584) * 256 + tid;
        if (id < ncnt4) ((int4*)cnt)[id] = make_int4(0, 0, 0, 0);
    } else {
        if (tid < 384) ((float4*)st)[tid] = make_float4(0.f, 0.f, 0.f, 0.f);
    }
}

// ---------------- combined CSR build (both layers) -------------------------
__global__ void count2_kernel(const int* __restrict__ d0, const int* __restrict__ e0, int E0,
                              const int* __restrict__ d1, const int* __restrict__ e1, int E1,
                              int* __restrict__ cnt, int* __restrict__ pos) {
    int e = blockIdx.x * 256 + threadIdx.x;
    if (e < E0) {
        pos[e] = atomicAdd(&cnt[e0[e] * ND0 + d0[e]], 1);
    } else if (e < E0 + E1) {
        int i = e - E0;
        pos[e] = atomicAdd(&cnt[NREL * ND0 + e1[i] * ND1 + d1[i]], 1);
    }
}

__global__ void scan_block_kernel(const int* __restrict__ in, int* __restrict__ out,
                                  int* __restrict__ bsum, int nb) {
    __shared__ int ts[256];
    int tid = threadIdx.x;
    int base = blockIdx.x * 1024 + tid * 4;
    int v0 = (base + 0 < nb) ? in[base + 0] : 0;
    int v1 = (base + 1 < nb) ? in[base + 1] : 0;
    int v2 = (base + 2 < nb) ? in[base + 2] : 0;
    int v3 = (base + 3 < nb) ? in[base + 3] : 0;
    int tsum = v0 + v1 + v2 + v3;
    ts[tid] = tsum;
    __syncthreads();
    for (int d = 1; d < 256; d <<= 1) {
        int t = (tid >= d) ? ts[tid - d] : 0;
        __syncthreads();
        ts[tid] += t;
        __syncthreads();
    }
    int excl = ts[tid] - tsum;
    if (base + 0 < nb) out[base + 0] = excl;
    if (base + 1 < nb) out[base + 1] = excl + v0;
    if (base + 2 < nb) out[base + 2] = excl + v0 + v1;
    if (base + 3 < nb) out[base + 3] = excl + v0 + v1 + v2;
    if (tid == 255 && bsum) bsum[blockIdx.x] = ts[255];
}

// fill2 with fused scan_add: final off = off[b] + bsum[b>>10]
__global__ void fill2_kernel(const int* __restrict__ s0, const int* __restrict__ d0,
                             const int* __restrict__ e0, int E0,
                             const int* __restrict__ s1, const int* __restrict__ d1,
                             const int* __restrict__ e1, int E1,
                             const int* __restrict__ pos, const int* __restrict__ off,
                             const int* __restrict__ bsum,
                             int* __restrict__ ssrc) {
    int e = blockIdx.x * 256 + threadIdx.x;
    if (e < E0) {
        int bb = e0[e] * ND0 + d0[e];
        ssrc[off[bb] + bsum[bb >> 10] + pos[e]] = s0[e];
    } else if (e < E0 + E1) {
        int i = e - E0;
        int bb = NREL * ND0 + e1[i] * ND1 + d1[i];
        ssrc[off[bb] + bsum[bb >> 10] + pos[e]] = s1[i];
    }
}

// ---------------- gather-sum: half-wave edge pairing (R11 body) ------------
__global__ void gather_kernel(const ushort_t* __restrict__ feat, const int* __restrict__ ssrc,
                              const int* __restrict__ cnt, const int* __restrict__ off,
                              const int* __restrict__ bsum, int bktbase,
                              int nbuckets, ushort_t* __restrict__ out,
                              const float* __restrict__ bnst, const float* __restrict__ bng,
                              const float* __restrict__ bnbe, float bninv) {
    __shared__ float scL[256], shL[256];
    if (bnst) {
        int c = threadIdx.x;
        float mu = bnst[c] * bninv;
        float var = bnst[HD + c] * bninv - mu * mu;
        float s = bng[c] * rsqrtf(var + EPS);
        scL[c] = s; shL[c] = bnbe[c] - mu * s;
        __syncthreads();
    }
    int wave = (blockIdx.x * 256 + threadIdx.x) >> 6;
    int lane = threadIdx.x & 63;
    if (wave >= nbuckets) return;
    int gb = bktbase + wave;
    int deg = cnt[gb], s = off[gb] + bsum[gb >> 10];
    int half = lane >> 5;          // 0: even edges, 1: odd edges
    int cl = lane & 31;            // channel group: cols [cl*8, cl*8+8)
    float a[8] = {0.f, 0.f, 0.f, 0.f, 0.f, 0.f, 0.f, 0.f};
    if (bnst) {
        float4 s0v = ((const float4*)scL)[cl * 2], s1v = ((const float4*)scL)[cl * 2 + 1];
        float4 h0v = ((const float4*)shL)[cl * 2], h1v = ((const float4*)shL)[cl * 2 + 1];
        float scv[8] = {s0v.x, s0v.y, s0v.z, s0v.w, s1v.x, s1v.y, s1v.z, s1v.w};
        float shv[8] = {h0v.x, h0v.y, h0v.z, h0v.w, h1v.x, h1v.y, h1v.z, h1v.w};
        int j = half;
        for (; j + 2 < deg; j += 4) {
            int r0 = ssrc[s + j], r1 = ssrc[s + j + 2];
            uint4 v0 = *(const uint4*)(feat + (size_t)r0 * HD + cl * 8);
            uint4 v1 = *(const uint4*)(feat + (size_t)r1 * HD + cl * 8);
            const ushort_t* u0 = (const ushort_t*)&v0;
            const ushort_t* u1 = (const ushort_t*)&v1;
#pragma unroll
            for (int i = 0; i < 8; i++) {
                float f0 = fmaf(b2f(u0[i]), scv[i], shv[i]);
                float f1 = fmaf(b2f(u1[i]), scv[i], shv[i]);
                a[i] += (f0 > 0.f ? f0 : expm1f(f0)) + (f1 > 0.f ? f1 : expm1f(f1));
            }
        }
        if (j < deg) {
            int r = ssrc[s + j];
            uint4 v = *(const uint4*)(feat + (size_t)r * HD + cl * 8);
            const ushort_t* u = (const ushort_t*)&v;
#pragma unroll
            for (int i = 0; i < 8; i++) {
                float f = fmaf(b2f(u[i]), scv[i], shv[i]);
                a[i] += f > 0.f ? f : expm1f(f);
            }
        }
    } else {
        int j = half;
        for (; j + 2 < deg; j += 4) {
            int r0 = ssrc[s + j], r1 = ssrc[s + j + 2];
            uint4 v0 = *(const uint4*)(feat + (size_t)r0 * HD + cl * 8);
            uint4 v1 = *(const uint4*)(feat + (size_t)r1 * HD + cl * 8);
            const ushort_t* u0 = (const ushort_t*)&v0;
            const ushort_t* u1 = (const ushort_t*)&v1;
#pragma unroll
            for (int i = 0; i < 8; i++) a[i] += b2f(u0[i]) + b2f(u1[i]);
        }
        if (j < deg) {
            int r = ssrc[s + j];
            uint4 v = *(const uint4*)(feat + (size_t)r * HD + cl * 8);
            const ushort_t* u = (const ushort_t*)&v;
#pragma unroll
            for (int i = 0; i < 8; i++) a[i] += b2f(u[i]);
        }
    }
#pragma unroll
    for (int i = 0; i < 8; i++) a[i] += __shfl_xor(a[i], 32);
    if (half == 0) {
        ushort_t o[8];
#pragma unroll
        for (int i = 0; i < 8; i++) o[i] = f2b(a[i]);
        *(uint4*)(out + (size_t)wave * HD + cl * 8) = *(const uint4*)o;
    }
}

// ---------------- fused MFMA GEMM (R5 body, BMxBN parameterized) -----------
// C = sum_s act(BN(A_s)) @ B_s + bias (BN+act only on seg fseg, params
// computed in-block from stats); optional per-column stats epilogue.
// LDS fragment-major (conflict-free), raw segs via global_load_lds, fused
// seg reg-stages. 4 waves: wave w owns (wm,wn) = ((w>>1)*BM/2, (w&1)*BN/2).
struct Seg {
    const ushort_t* A;
    const ushort_t* B;
};
struct GemmArgs {
    Seg seg[6];
    int nseg;
    int fseg;            // -1 = none; else segment with fused BN+act
    int fact;            // 1=ELU, 2=ReLU
    const float* fst;    // stats [512] for fused seg
    const float* fg;
    const float* fbe;
    float finv;
    const float* bias;
    float* stats;        // null or [512]: colsum, colsumsq
    ushort_t* Cb;        // bf16 out, stride 256 (or null)
    float* Cf;           // fp32 out, stride N
    int M, N;
};

template <int BM, int BN, int MINW>
__launch_bounds__(256, MINW)
__global__ void gemm_mfma_kernel(GemmArgs g) {
    constexpr int FM  = BM / 32;        // per-wave M frags
    constexpr int FN  = BN / 32;        // per-wave N frags
    constexpr int NFA = BM / 8;         // A fragtiles per K-step (BM/16 * 2)
    constexpr int NFB = BN / 8;
    constexpr int ITA = NFA / 4;
    constexpr int ITB = NFB / 4;
    __shared__ __align__(1024) ushort_t As[NFA * 512];
    __shared__ __align__(1024) ushort_t Bs[NFB * 512];
    __shared__ float scL[256], shL[256];
    int tid = threadIdx.x;
    if (g.fseg >= 0) {
        int c = tid;
        float mu = g.fst[c] * g.finv;
        float var = g.fst[HD + c] * g.finv - mu * mu;
        float s = g.fg[c] * rsqrtf(var + EPS);
        scL[c] = s; shL[c] = g.fbe[c] - mu * s;
        __syncthreads();
    }
    int wave = tid >> 6, lane = tid & 63;
    int rq = lane >> 4, ci = lane & 15;
    int wm = (wave >> 1) * (BM / 2), wn = (wave & 1) * (BN / 2);
    int bm = blockIdx.y * BM, bn = blockIdx.x * BN;
    f32x4 acc[FM][FN] = {};
    int K = g.nseg * HD;

    for (int kk = 0; kk < K; kk += BK) {
        int si = kk >> 8;
        int kl = kk & 255;
        const ushort_t* Ap = g.seg[si].A;
        const ushort_t* Bp = g.seg[si].B;
        if (si != g.fseg) {
#pragma unroll
            for (int it = 0; it < ITA; it++) {
                int f = it * 4 + wave;            // fragtile id
                int mt = f >> 1, kt = f & 1;
                const ushort_t* ga = Ap + (size_t)(bm + mt * 16 + ci) * HD
                                        + kl + kt * 32 + rq * 8;
                GLOAD_LDS16(ga, &As[f * 512 + lane * 8]);
            }
        } else {
            int act = g.fact;
#pragma unroll
            for (int it = 0; it < ITA; it++) {
                int f = it * 4 + wave;
                int mt = f >> 1, kt = f & 1;
                int kb = kl + kt * 32 + rq * 8;
                uint4 v = *(const uint4*)(Ap + (size_t)(bm + mt * 16 + ci) * HD + kb);
                ushort_t* u = (ushort_t*)&v;
#pragma unroll
                for (int j = 0; j < 8; j++) {
                    float fv = fmaf(b2f(u[j]), scL[kb + j], shL[kb + j]);
                    fv = (act == 2) ? fmaxf(fv, 0.f) : (fv > 0.f ? fv : expm1f(fv));
                    u[j] = f2b(fv);
                }
                *(uint4*)&As[f * 512 + lane * 8] = v;
            }
        }
#pragma unroll
        for (int it = 0; it < ITB; it++) {
            int f = it * 4 + wave;
            int nt = f >> 1, kt = f & 1;
            const ushort_t* gb = Bp + (size_t)(bn + nt * 16 + ci) * HD
                                    + kl + kt * 32 + rq * 8;
            GLOAD_LDS16(gb, &Bs[f * 512 + lane * 8]);
        }
        __syncthreads();
#pragma unroll
        for (int ks = 0; ks < 2; ks++) {
            short8 a[FM], b[FN];
#pragma unroll
            for (int mi = 0; mi < FM; mi++)
                a[mi] = *(const short8*)&As[((wm / 16 + mi) * 2 + ks) * 512 + lane * 8];
#pragma unroll
            for (int ni = 0; ni < FN; ni++)
                b[ni] = *(const short8*)&Bs[((wn / 16 + ni) * 2 + ks) * 512 + lane * 8];
#pragma unroll
            for (int mi = 0; mi < FM; mi++)
#pragma unroll
                for (int ni = 0; ni < FN; ni++)
                    acc[mi][ni] = __builtin_amdgcn_mfma_f32_16x16x32_bf16(
                        a[mi], b[ni], acc[mi][ni], 0, 0, 0);
        }
        __syncthreads();
    }

    // bias (before stats, matching reference h = agg + bias)
#pragma unroll
    for (int ni = 0; ni < FN; ni++) {
        int col = bn + wn + ni * 16 + ci;
        float bv = (col < g.N) ? g.bias[col] : 0.f;
#pragma unroll
        for (int mi = 0; mi < FM; mi++)
#pragma unroll
            for (int reg = 0; reg < 4; reg++) acc[mi][ni][reg] += bv;
    }
    // fused BN stats (fp32, pre-rounding)
    if (g.stats) {
#pragma unroll
        for (int ni = 0; ni < FN; ni++) {
            float s = 0.f, s2 = 0.f;
#pragma unroll
            for (int mi = 0; mi < FM; mi++)
#pragma unroll
                for (int reg = 0; reg < 4; reg++) {
                    int row = bm + wm + mi * 16 + rq * 4 + reg;
                    if (row < g.M) { float v = acc[mi][ni][reg]; s += v; s2 += v * v; }
                }
            s  += __shfl_xor(s, 16);  s  += __shfl_xor(s, 32);
            s2 += __shfl_xor(s2, 16); s2 += __shfl_xor(s2, 32);
            if (rq == 0) {
                int col = bn + wn + ni * 16 + ci;
                atomicAdd(&g.stats[col], s);
                atomicAdd(&g.stats[HD + col], s2);
            }
        }
    }
#pragma unroll
    for (int mi = 0; mi < FM; mi++)
#pragma unroll
        for (int ni = 0; ni < FN; ni++)
#pragma unroll
            for (int reg = 0; reg < 4; reg++) {
                int row = bm + wm + mi * 16 + rq * 4 + reg;
                int col = bn + wn + ni * 16 + ci;
                if (row < g.M && col < g.N) {
                    float v = acc[mi][ni][reg];
                    if (g.Cb) g.Cb[(size_t)row * HD + col] = f2b(v);
                    else      g.Cf[(size_t)row * g.N + col] = v;
                }
            }
}

// ---------------------------------------------------------------------------
extern "C" void kernel_launch(void* const* d_in, const int* in_sizes, int n_in,
                              void* d_out, int out_size, void* d_ws, size_t ws_size,
                              hipStream_t stream) {
    const float* x   = (const float*)d_in[0];
    const int* src0  = (const int*)d_in[1];
    const int* dst0  = (const int*)d_in[2];
    const int* et0   = (const int*)d_in[3];
    const int* src1  = (const int*)d_in[4];
    const int* dst1  = (const int*)d_in[5];
    const int* et1   = (const int*)d_in[6];
    const float* W0  = (const float*)d_in[9];
    const float* Wl0 = (const float*)d_in[10];
    const float* b0  = (const float*)d_in[11];
    const float* g0  = (const float*)d_in[12];
    const float* be0 = (const float*)d_in[13];
    const float* W1  = (const float*)d_in[14];
    const float* Wl1 = (const float*)d_in[15];
    const float* b1  = (const float*)d_in[16];
    const float* g1  = (const float*)d_in[17];
    const float* be1 = (const float*)d_in[18];
    const float* Wm1 = (const float*)d_in[19];
    const float* bm1 = (const float*)d_in[20];
    const float* gm  = (const float*)d_in[21];
    const float* bem = (const float*)d_in[22];
    const float* Wm2 = (const float*)d_in[23];
    const float* bm2 = (const float*)d_in[24];

    const int E0 = in_sizes[1];
    const int E1 = in_sizes[4];
    const int NOUT = in_sizes[24];     // 153
    const int NSRC = in_sizes[0] / HD; // 200000
    const int NBKT = NREL * ND0 + NREL * ND1;  // 300000

    // ---------------- ws layout (~305 MB) ----------------------------------
    char* p = (char*)d_ws;
    ushort_t* Wt = (ushort_t*)p;  p += (size_t)14 * 65536 * 2;
    float* st    = (float*)p;     p += 1536 * 4;    // st0 | st1 | stm (512 ea)
    int* cnt     = (int*)p;       p += (size_t)NBKT * 4;
    int* off     = (int*)p;       p += (size_t)NBKT * 4;
    int* bsum    = (int*)p;       p += 1024 * 4;
    int* pos     = (int*)p;       p += (size_t)(E0 + E1) * 4;
    int* ssrc    = (int*)p;       p += (size_t)(E0 + E1) * 4;
    ushort_t* xb  = (ushort_t*)p; p += (size_t)NSRC * HD * 2;
    ushort_t* S0  = (ushort_t*)p; p += (size_t)(NREL * ND0 + 128) * HD * 2;
    ushort_t* S1  = (ushort_t*)p; p += (size_t)(NREL * ND1 + 128) * HD * 2;
    ushort_t* h0b = (ushort_t*)p; p += (size_t)(ND0 + 128) * HD * 2;
    ushort_t* h1b = (ushort_t*)p; p += (size_t)(ND1 + 128) * HD * 2;
    ushort_t* mb  = (ushort_t*)p; p += (size_t)(ND1 + 128) * HD * 2;

    float* st0 = st, *st1 = st + 512, *stm = st + 1024;

    ushort_t* W0t  = Wt;
    ushort_t* Wl0t = Wt + 5 * 65536;
    ushort_t* W1t  = Wt + 6 * 65536;
    ushort_t* Wl1t = Wt + 11 * 65536;
    ushort_t* Wm1t = Wt + 12 * 65536;
    ushort_t* Wm2t = Wt + 13 * 65536;

    // ---------------- prep: weights + xb + zeroing (one kernel) ------------
    {
        WconvArgs wa;
        for (int r = 0; r < NREL; r++) { wa.src[r] = W0 + (size_t)r * 65536; wa.dst[r] = W0t + (size_t)r * 65536; wa.N[r] = 256; }
        wa.src[5] = Wl0; wa.dst[5] = Wl0t; wa.N[5] = 256;
        for (int r = 0; r < NREL; r++) { wa.src[6 + r] = W1 + (size_t)r * 65536; wa.dst[6 + r] = W1t + (size_t)r * 65536; wa.N[6 + r] = 256; }
        wa.src[11] = Wl1; wa.dst[11] = Wl1t; wa.N[11] = 256;
        wa.src[12] = Wm1; wa.dst[12] = Wm1t; wa.N[12] = 256;
        wa.src[13] = Wm2; wa.dst[13] = Wm2t; wa.N[13] = NOUT;
        int n4 = NSRC * 64;
        prep_kernel<<<53878, 256, 0, stream>>>(wa, x, xb, n4, cnt, NBKT / 4, st);
    }

    // ---------------- combined CSR (both layers) ---------------------------
    int ET = E0 + E1;
    count2_kernel<<<(ET + 255) / 256, 256, 0, stream>>>(dst0, et0, E0, dst1, et1, E1, cnt, pos);
    int nsb = (NBKT + 1023) / 1024;
    scan_block_kernel<<<nsb, 256, 0, stream>>>(cnt, off, bsum, NBKT);
    scan_block_kernel<<<1, 256, 0, stream>>>(bsum, bsum, nullptr, nsb);
    fill2_kernel<<<(ET + 255) / 256, 256, 0, stream>>>(src0, dst0, et0, E0, src1, dst1, et1, E1, pos, off, bsum, ssrc);

    // ---------------- layer 0: gather + fused GEMM (stats fused) -----------
    gather_kernel<<<(NREL * ND0 * 64) / 256, 256, 0, stream>>>(
        xb, ssrc, cnt, off, bsum, 0, NREL * ND0, S0, nullptr, nullptr, nullptr, 0.f);
    {
        GemmArgs ga = {};
        for (int s = 0; s < NREL; s++)
            ga.seg[s] = { S0 + (size_t)s * ND0 * HD, W0t + (size_t)s * 65536 };
        ga.seg[5] = { xb, Wl0t };
        ga.nseg = 6; ga.fseg = -1;
        ga.bias = b0; ga.stats = st0;
        ga.Cb = h0b; ga.Cf = nullptr; ga.M = ND0; ga.N = HD;
        gemm_mfma_kernel<64, 128, 4><<<dim3(2, (ND0 + 63) / 64), 256, 0, stream>>>(ga);
    }

    // ---------------- layer 1: gather (BN+ELU fused) + fused GEMM ----------
    gather_kernel<<<(NREL * ND1 * 64) / 256, 256, 0, stream>>>(
        h0b, ssrc, cnt, off, bsum, NREL * ND0, NREL * ND1, S1, st0, g0, be0, 1.f / ND0);
    {
        GemmArgs ga = {};
        for (int s = 0; s < NREL; s++)
            ga.seg[s] = { S1 + (size_t)s * ND1 * HD, W1t + (size_t)s * 65536 };
        ga.seg[5] = { h0b, Wl1t };
        ga.nseg = 6; ga.fseg = 5; ga.fact = 1;
        ga.fst = st0; ga.fg = g0; ga.fbe = be0; ga.finv = 1.f / ND0;
        ga.bias = b1; ga.stats = st1;
        ga.Cb = h1b; ga.Cf = nullptr; ga.M = ND1; ga.N = HD;
        gemm_mfma_kernel<64, 64, 4><<<dim3(4, (ND1 + 63) / 64), 256, 0, stream>>>(ga);
    }

    // ---------------- MLP head ---------------------------------------------
    {
        GemmArgs ga = {};
        ga.seg[0] = { h1b, Wm1t };
        ga.nseg = 1; ga.fseg = 0; ga.fact = 1;
        ga.fst = st1; ga.fg = g1; ga.fbe = be1; ga.finv = 1.f / ND1;
        ga.bias = bm1; ga.stats = stm;
        ga.Cb = mb; ga.Cf = nullptr; ga.M = ND1; ga.N = HD;
        gemm_mfma_kernel<64, 64, 4><<<dim3(4, (ND1 + 63) / 64), 256, 0, stream>>>(ga);
    }
    {
        GemmArgs ga = {};
        ga.seg[0] = { mb, Wm2t };
        ga.nseg = 1; ga.fseg = 0; ga.fact = 2;
        ga.fst = stm; ga.fg = gm; ga.fbe = bem; ga.finv = 1.f / ND1;
        ga.bias = bm2; ga.stats = nullptr;
        ga.Cb = nullptr; ga.Cf = (float*)d_out; ga.M = ND1; ga.N = NOUT;
        gemm_mfma_kernel<64, 64, 4><<<dim3((NOUT + 63) / 64, (ND1 + 63) / 64), 256, 0, stream>>>(ga);
    }
}

// Round 11
// 712.946 us; speedup vs baseline: 1.0576x; 1.0576x over previous
//
#include <hip/hip_runtime.h>
#include <hip/hip_bf16.h>

// ---------------------------------------------------------------------------
// DGLRGCN on MI355X. Round 15: tile-shape law from R5/R7/R8/R14 evidence --
// per-CU stall metric ~ (BM+BN)/(BM*BN); maximize harmonic mean of BM,BN
// subject to >=2 blocks/CU co-residency. L0 GEMM: BM256 x BN128 (HM=170 vs
// 128 for 128^2): grid (2,196), 24 K-steps/block, LDS 50KB -> 2-3 blocks/CU.
// Same R5 fragment-major gload_lds body, parameterized only. Row pads
// +128 -> +256 for the BM=256 tail. Small GEMMs / gather / CSR / prep =
// byte-identical to R11 (737us anchor). R14 (BM64xBN128, HM=85) measured
// 1.23x WORSE -- model-consistent; this goes the opposite direction.
// ---------------------------------------------------------------------------

#define HD   256
#define EPS  1e-5f
#define NREL 5
#define ND0  50000
#define ND1  10000
#define BK   64

typedef unsigned short ushort_t;
using f32x4  = __attribute__((ext_vector_type(4))) float;
using short8 = __attribute__((ext_vector_type(8))) short;

__device__ __forceinline__ ushort_t f2b(float f) {
    union { float f; unsigned u; } x; x.f = f;
    unsigned r = x.u + 0x7FFF + ((x.u >> 16) & 1);   // RNE
    return (ushort_t)(r >> 16);
}
__device__ __forceinline__ float b2f(ushort_t h) {
    union { unsigned u; float f; } x; x.u = ((unsigned)h) << 16;
    return x.f;
}

// global(16B) -> LDS DMA, one wave-instruction covers 1024B (64 lanes x 16B)
#define GLOAD_LDS16(gp, lp)                                                     \
    __builtin_amdgcn_global_load_lds(                                           \
        (const __attribute__((address_space(1))) unsigned int*)(gp),            \
        (__attribute__((address_space(3))) unsigned int*)(lp), 16, 0, 0)

// ---------------- prep: weights conv + x conv + zeroing (one kernel) -------
struct WconvArgs {
    const float* src[14];
    ushort_t*    dst[14];
    int          N[14];
};
// sections: [0,3584) wconv | [3584,53584) xconv | [53584,53877) cnt | [53877] st
__global__ void prep_kernel(WconvArgs a, const float* __restrict__ x,
                            ushort_t* __restrict__ xb, int n4,
                            int* __restrict__ cnt, int ncnt4,
                            float* __restrict__ st) {
    int b = blockIdx.x;
    int tid = threadIdx.x;
    if (b < 3584) {
        int mat = b >> 8;
        int id = (b & 255) * 256 + tid;     // 0..65535
        int n = id >> 8, k = id & 255;
        int N = a.N[mat];
        float v = (n < N) ? a.src[mat][(size_t)k * N + n] : 0.f;
        a.dst[mat][id] = f2b(v);
    } else if (b < 53584) {
        int id = (b - 3584) * 256 + tid;
        if (id < n4) {
            float4 v = ((const float4*)x)[id];
            ushort4 o; o.x = f2b(v.x); o.y = f2b(v.y); o.z = f2b(v.z); o.w = f2b(v.w);
            ((ushort4*)xb)[id] = o;
        }
    } else if (b < 53877) {
        int id = (b - 53584) * 256 + tid;
        if (id < ncnt4) ((int4*)cnt)[id] = make_int4(0, 0, 0, 0);
    } else {
        if (tid < 384) ((float4*)st)[tid] = make_float4(0.f, 0.f, 0.f, 0.f);
    }
}

// ---------------- combined CSR build (both layers) -------------------------
__global__ void count2_kernel(const int* __restrict__ d0, const int* __restrict__ e0, int E0,
                              const int* __restrict__ d1, const int* __restrict__ e1, int E1,
                              int* __restrict__ cnt, int* __restrict__ pos) {
    int e = blockIdx.x * 256 + threadIdx.x;
    if (e < E0) {
        pos[e] = atomicAdd(&cnt[e0[e] * ND0 + d0[e]], 1);
    } else if (e < E0 + E1) {
        int i = e - E0;
        pos[e] = atomicAdd(&cnt[NREL * ND0 + e1[i] * ND1 + d1[i]], 1);
    }
}

__global__ void scan_block_kernel(const int* __restrict__ in, int* __restrict__ out,
                                  int* __restrict__ bsum, int nb) {
    __shared__ int ts[256];
    int tid = threadIdx.x;
    int base = blockIdx.x * 1024 + tid * 4;
    int v0 = (base + 0 < nb) ? in[base + 0] : 0;
    int v1 = (base + 1 < nb) ? in[base + 1] : 0;
    int v2 = (base + 2 < nb) ? in[base + 2] : 0;
    int v3 = (base + 3 < nb) ? in[base + 3] : 0;
    int tsum = v0 + v1 + v2 + v3;
    ts[tid] = tsum;
    __syncthreads();
    for (int d = 1; d < 256; d <<= 1) {
        int t = (tid >= d) ? ts[tid - d] : 0;
        __syncthreads();
        ts[tid] += t;
        __syncthreads();
    }
    int excl = ts[tid] - tsum;
    if (base + 0 < nb) out[base + 0] = excl;
    if (base + 1 < nb) out[base + 1] = excl + v0;
    if (base + 2 < nb) out[base + 2] = excl + v0 + v1;
    if (base + 3 < nb) out[base + 3] = excl + v0 + v1 + v2;
    if (tid == 255 && bsum) bsum[blockIdx.x] = ts[255];
}

// fill2 with fused scan_add: final off = off[b] + bsum[b>>10]
__global__ void fill2_kernel(const int* __restrict__ s0, const int* __restrict__ d0,
                             const int* __restrict__ e0, int E0,
                             const int* __restrict__ s1, const int* __restrict__ d1,
                             const int* __restrict__ e1, int E1,
                             const int* __restrict__ pos, const int* __restrict__ off,
                             const int* __restrict__ bsum,
                             int* __restrict__ ssrc) {
    int e = blockIdx.x * 256 + threadIdx.x;
    if (e < E0) {
        int bb = e0[e] * ND0 + d0[e];
        ssrc[off[bb] + bsum[bb >> 10] + pos[e]] = s0[e];
    } else if (e < E0 + E1) {
        int i = e - E0;
        int bb = NREL * ND0 + e1[i] * ND1 + d1[i];
        ssrc[off[bb] + bsum[bb >> 10] + pos[e]] = s1[i];
    }
}

// ---------------- gather-sum: half-wave edge pairing (R11 body) ------------
__global__ void gather_kernel(const ushort_t* __restrict__ feat, const int* __restrict__ ssrc,
                              const int* __restrict__ cnt, const int* __restrict__ off,
                              const int* __restrict__ bsum, int bktbase,
                              int nbuckets, ushort_t* __restrict__ out,
                              const float* __restrict__ bnst, const float* __restrict__ bng,
                              const float* __restrict__ bnbe, float bninv) {
    __shared__ float scL[256], shL[256];
    if (bnst) {
        int c = threadIdx.x;
        float mu = bnst[c] * bninv;
        float var = bnst[HD + c] * bninv - mu * mu;
        float s = bng[c] * rsqrtf(var + EPS);
        scL[c] = s; shL[c] = bnbe[c] - mu * s;
        __syncthreads();
    }
    int wave = (blockIdx.x * 256 + threadIdx.x) >> 6;
    int lane = threadIdx.x & 63;
    if (wave >= nbuckets) return;
    int gb = bktbase + wave;
    int deg = cnt[gb], s = off[gb] + bsum[gb >> 10];
    int half = lane >> 5;          // 0: even edges, 1: odd edges
    int cl = lane & 31;            // channel group: cols [cl*8, cl*8+8)
    float a[8] = {0.f, 0.f, 0.f, 0.f, 0.f, 0.f, 0.f, 0.f};
    if (bnst) {
        float4 s0v = ((const float4*)scL)[cl * 2], s1v = ((const float4*)scL)[cl * 2 + 1];
        float4 h0v = ((const float4*)shL)[cl * 2], h1v = ((const float4*)shL)[cl * 2 + 1];
        float scv[8] = {s0v.x, s0v.y, s0v.z, s0v.w, s1v.x, s1v.y, s1v.z, s1v.w};
        float shv[8] = {h0v.x, h0v.y, h0v.z, h0v.w, h1v.x, h1v.y, h1v.z, h1v.w};
        int j = half;
        for (; j + 2 < deg; j += 4) {
            int r0 = ssrc[s + j], r1 = ssrc[s + j + 2];
            uint4 v0 = *(const uint4*)(feat + (size_t)r0 * HD + cl * 8);
            uint4 v1 = *(const uint4*)(feat + (size_t)r1 * HD + cl * 8);
            const ushort_t* u0 = (const ushort_t*)&v0;
            const ushort_t* u1 = (const ushort_t*)&v1;
#pragma unroll
            for (int i = 0; i < 8; i++) {
                float f0 = fmaf(b2f(u0[i]), scv[i], shv[i]);
                float f1 = fmaf(b2f(u1[i]), scv[i], shv[i]);
                a[i] += (f0 > 0.f ? f0 : expm1f(f0)) + (f1 > 0.f ? f1 : expm1f(f1));
            }
        }
        if (j < deg) {
            int r = ssrc[s + j];
            uint4 v = *(const uint4*)(feat + (size_t)r * HD + cl * 8);
            const ushort_t* u = (const ushort_t*)&v;
#pragma unroll
            for (int i = 0; i < 8; i++) {
                float f = fmaf(b2f(u[i]), scv[i], shv[i]);
                a[i] += f > 0.f ? f : expm1f(f);
            }
        }
    } else {
        int j = half;
        for (; j + 2 < deg; j += 4) {
            int r0 = ssrc[s + j], r1 = ssrc[s + j + 2];
            uint4 v0 = *(const uint4*)(feat + (size_t)r0 * HD + cl * 8);
            uint4 v1 = *(const uint4*)(feat + (size_t)r1 * HD + cl * 8);
            const ushort_t* u0 = (const ushort_t*)&v0;
            const ushort_t* u1 = (const ushort_t*)&v1;
#pragma unroll
            for (int i = 0; i < 8; i++) a[i] += b2f(u0[i]) + b2f(u1[i]);
        }
        if (j < deg) {
            int r = ssrc[s + j];
            uint4 v = *(const uint4*)(feat + (size_t)r * HD + cl * 8);
            const ushort_t* u = (const ushort_t*)&v;
#pragma unroll
            for (int i = 0; i < 8; i++) a[i] += b2f(u[i]);
        }
    }
#pragma unroll
    for (int i = 0; i < 8; i++) a[i] += __shfl_xor(a[i], 32);
    if (half == 0) {
        ushort_t o[8];
#pragma unroll
        for (int i = 0; i < 8; i++) o[i] = f2b(a[i]);
        *(uint4*)(out + (size_t)wave * HD + cl * 8) = *(const uint4*)o;
    }
}

// ---------------- fused MFMA GEMM (R5 body, BMxBN parameterized) -----------
// C = sum_s act(BN(A_s)) @ B_s + bias (BN+act only on seg fseg, params
// computed in-block from stats); optional per-column stats epilogue.
// LDS fragment-major (conflict-free), raw segs via global_load_lds, fused
// seg reg-stages. 4 waves: wave w owns (wm,wn) = ((w>>1)*BM/2, (w&1)*BN/2).
struct Seg {
    const ushort_t* A;
    const ushort_t* B;
};
struct GemmArgs {
    Seg seg[6];
    int nseg;
    int fseg;            // -1 = none; else segment with fused BN+act
    int fact;            // 1=ELU, 2=ReLU
    const float* fst;    // stats [512] for fused seg
    const float* fg;
    const float* fbe;
    float finv;
    const float* bias;
    float* stats;        // null or [512]: colsum, colsumsq
    ushort_t* Cb;        // bf16 out, stride 256 (or null)
    float* Cf;           // fp32 out, stride N
    int M, N;
};

template <int BM, int BN, int MINW>
__launch_bounds__(256, MINW)
__global__ void gemm_mfma_kernel(GemmArgs g) {
    constexpr int FM  = BM / 32;        // per-wave M frags
    constexpr int FN  = BN / 32;        // per-wave N frags
    constexpr int NFA = BM / 8;         // A fragtiles per K-step (BM/16 * 2)
    constexpr int NFB = BN / 8;
    constexpr int ITA = NFA / 4;
    constexpr int ITB = NFB / 4;
    __shared__ __align__(1024) ushort_t As[NFA * 512];
    __shared__ __align__(1024) ushort_t Bs[NFB * 512];
    __shared__ float scL[256], shL[256];
    int tid = threadIdx.x;
    if (g.fseg >= 0) {
        int c = tid;
        float mu = g.fst[c] * g.finv;
        float var = g.fst[HD + c] * g.finv - mu * mu;
        float s = g.fg[c] * rsqrtf(var + EPS);
        scL[c] = s; shL[c] = g.fbe[c] - mu * s;
        __syncthreads();
    }
    int wave = tid >> 6, lane = tid & 63;
    int rq = lane >> 4, ci = lane & 15;
    int wm = (wave >> 1) * (BM / 2), wn = (wave & 1) * (BN / 2);
    int bm = blockIdx.y * BM, bn = blockIdx.x * BN;
    f32x4 acc[FM][FN] = {};
    int K = g.nseg * HD;

    for (int kk = 0; kk < K; kk += BK) {
        int si = kk >> 8;
        int kl = kk & 255;
        const ushort_t* Ap = g.seg[si].A;
        const ushort_t* Bp = g.seg[si].B;
        if (si != g.fseg) {
#pragma unroll
            for (int it = 0; it < ITA; it++) {
                int f = it * 4 + wave;            // fragtile id
                int mt = f >> 1, kt = f & 1;
                const ushort_t* ga = Ap + (size_t)(bm + mt * 16 + ci) * HD
                                        + kl + kt * 32 + rq * 8;
                GLOAD_LDS16(ga, &As[f * 512 + lane * 8]);
            }
        } else {
            int act = g.fact;
#pragma unroll
            for (int it = 0; it < ITA; it++) {
                int f = it * 4 + wave;
                int mt = f >> 1, kt = f & 1;
                int kb = kl + kt * 32 + rq * 8;
                uint4 v = *(const uint4*)(Ap + (size_t)(bm + mt * 16 + ci) * HD + kb);
                ushort_t* u = (ushort_t*)&v;
#pragma unroll
                for (int j = 0; j < 8; j++) {
                    float fv = fmaf(b2f(u[j]), scL[kb + j], shL[kb + j]);
                    fv = (act == 2) ? fmaxf(fv, 0.f) : (fv > 0.f ? fv : expm1f(fv));
                    u[j] = f2b(fv);
                }
                *(uint4*)&As[f * 512 + lane * 8] = v;
            }
        }
#pragma unroll
        for (int it = 0; it < ITB; it++) {
            int f = it * 4 + wave;
            int nt = f >> 1, kt = f & 1;
            const ushort_t* gb = Bp + (size_t)(bn + nt * 16 + ci) * HD
                                    + kl + kt * 32 + rq * 8;
            GLOAD_LDS16(gb, &Bs[f * 512 + lane * 8]);
        }
        __syncthreads();
#pragma unroll
        for (int ks = 0; ks < 2; ks++) {
            short8 a[FM], b[FN];
#pragma unroll
            for (int mi = 0; mi < FM; mi++)
                a[mi] = *(const short8*)&As[((wm / 16 + mi) * 2 + ks) * 512 + lane * 8];
#pragma unroll
            for (int ni = 0; ni < FN; ni++)
                b[ni] = *(const short8*)&Bs[((wn / 16 + ni) * 2 + ks) * 512 + lane * 8];
#pragma unroll
            for (int mi = 0; mi < FM; mi++)
#pragma unroll
                for (int ni = 0; ni < FN; ni++)
                    acc[mi][ni] = __builtin_amdgcn_mfma_f32_16x16x32_bf16(
                        a[mi], b[ni], acc[mi][ni], 0, 0, 0);
        }
        __syncthreads();
    }

    // bias (before stats, matching reference h = agg + bias)
#pragma unroll
    for (int ni = 0; ni < FN; ni++) {
        int col = bn + wn + ni * 16 + ci;
        float bv = (col < g.N) ? g.bias[col] : 0.f;
#pragma unroll
        for (int mi = 0; mi < FM; mi++)
#pragma unroll
            for (int reg = 0; reg < 4; reg++) acc[mi][ni][reg] += bv;
    }
    // fused BN stats (fp32, pre-rounding)
    if (g.stats) {
#pragma unroll
        for (int ni = 0; ni < FN; ni++) {
            float s = 0.f, s2 = 0.f;
#pragma unroll
            for (int mi = 0; mi < FM; mi++)
#pragma unroll
                for (int reg = 0; reg < 4; reg++) {
                    int row = bm + wm + mi * 16 + rq * 4 + reg;
                    if (row < g.M) { float v = acc[mi][ni][reg]; s += v; s2 += v * v; }
                }
            s  += __shfl_xor(s, 16);  s  += __shfl_xor(s, 32);
            s2 += __shfl_xor(s2, 16); s2 += __shfl_xor(s2, 32);
            if (rq == 0) {
                int col = bn + wn + ni * 16 + ci;
                atomicAdd(&g.stats[col], s);
                atomicAdd(&g.stats[HD + col], s2);
            }
        }
    }
#pragma unroll
    for (int mi = 0; mi < FM; mi++)
#pragma unroll
        for (int ni = 0; ni < FN; ni++)
#pragma unroll
            for (int reg = 0; reg < 4; reg++) {
                int row = bm + wm + mi * 16 + rq * 4 + reg;
                int col = bn + wn + ni * 16 + ci;
                if (row < g.M && col < g.N) {
                    float v = acc[mi][ni][reg];
                    if (g.Cb) g.Cb[(size_t)row * HD + col] = f2b(v);
                    else      g.Cf[(size_t)row * g.N + col] = v;
                }
            }
}

// ---------------------------------------------------------------------------
extern "C" void kernel_launch(void* const* d_in, const int* in_sizes, int n_in,
                              void* d_out, int out_size, void* d_ws, size_t ws_size,
                              hipStream_t stream) {
    const float* x   = (const float*)d_in[0];
    const int* src0  = (const int*)d_in[1];
    const int* dst0  = (const int*)d_in[2];
    const int* et0   = (const int*)d_in[3];
    const int* src1  = (const int*)d_in[4];
    const int* dst1  = (const int*)d_in[5];
    const int* et1   = (const int*)d_in[6];
    const float* W0  = (const float*)d_in[9];
    const float* Wl0 = (const float*)d_in[10];
    const float* b0  = (const float*)d_in[11];
    const float* g0  = (const float*)d_in[12];
    const float* be0 = (const float*)d_in[13];
    const float* W1  = (const float*)d_in[14];
    const float* Wl1 = (const float*)d_in[15];
    const float* b1  = (const float*)d_in[16];
    const float* g1  = (const float*)d_in[17];
    const float* be1 = (const float*)d_in[18];
    const float* Wm1 = (const float*)d_in[19];
    const float* bm1 = (const float*)d_in[20];
    const float* gm  = (const float*)d_in[21];
    const float* bem = (const float*)d_in[22];
    const float* Wm2 = (const float*)d_in[23];
    const float* bm2 = (const float*)d_in[24];

    const int E0 = in_sizes[1];
    const int E1 = in_sizes[4];
    const int NOUT = in_sizes[24];     // 153
    const int NSRC = in_sizes[0] / HD; // 200000
    const int NBKT = NREL * ND0 + NREL * ND1;  // 300000

    // ---------------- ws layout (~305 MB) ----------------------------------
    char* p = (char*)d_ws;
    ushort_t* Wt = (ushort_t*)p;  p += (size_t)14 * 65536 * 2;
    float* st    = (float*)p;     p += 1536 * 4;    // st0 | st1 | stm (512 ea)
    int* cnt     = (int*)p;       p += (size_t)NBKT * 4;
    int* off     = (int*)p;       p += (size_t)NBKT * 4;
    int* bsum    = (int*)p;       p += 1024 * 4;
    int* pos     = (int*)p;       p += (size_t)(E0 + E1) * 4;
    int* ssrc    = (int*)p;       p += (size_t)(E0 + E1) * 4;
    ushort_t* xb  = (ushort_t*)p; p += (size_t)NSRC * HD * 2;
    ushort_t* S0  = (ushort_t*)p; p += (size_t)(NREL * ND0 + 256) * HD * 2;
    ushort_t* S1  = (ushort_t*)p; p += (size_t)(NREL * ND1 + 256) * HD * 2;
    ushort_t* h0b = (ushort_t*)p; p += (size_t)(ND0 + 256) * HD * 2;
    ushort_t* h1b = (ushort_t*)p; p += (size_t)(ND1 + 256) * HD * 2;
    ushort_t* mb  = (ushort_t*)p; p += (size_t)(ND1 + 256) * HD * 2;

    float* st0 = st, *st1 = st + 512, *stm = st + 1024;

    ushort_t* W0t  = Wt;
    ushort_t* Wl0t = Wt + 5 * 65536;
    ushort_t* W1t  = Wt + 6 * 65536;
    ushort_t* Wl1t = Wt + 11 * 65536;
    ushort_t* Wm1t = Wt + 12 * 65536;
    ushort_t* Wm2t = Wt + 13 * 65536;

    // ---------------- prep: weights + xb + zeroing (one kernel) ------------
    {
        WconvArgs wa;
        for (int r = 0; r < NREL; r++) { wa.src[r] = W0 + (size_t)r * 65536; wa.dst[r] = W0t + (size_t)r * 65536; wa.N[r] = 256; }
        wa.src[5] = Wl0; wa.dst[5] = Wl0t; wa.N[5] = 256;
        for (int r = 0; r < NREL; r++) { wa.src[6 + r] = W1 + (size_t)r * 65536; wa.dst[6 + r] = W1t + (size_t)r * 65536; wa.N[6 + r] = 256; }
        wa.src[11] = Wl1; wa.dst[11] = Wl1t; wa.N[11] = 256;
        wa.src[12] = Wm1; wa.dst[12] = Wm1t; wa.N[12] = 256;
        wa.src[13] = Wm2; wa.dst[13] = Wm2t; wa.N[13] = NOUT;
        int n4 = NSRC * 64;
        prep_kernel<<<53878, 256, 0, stream>>>(wa, x, xb, n4, cnt, NBKT / 4, st);
    }

    // ---------------- combined CSR (both layers) ---------------------------
    int ET = E0 + E1;
    count2_kernel<<<(ET + 255) / 256, 256, 0, stream>>>(dst0, et0, E0, dst1, et1, E1, cnt, pos);
    int nsb = (NBKT + 1023) / 1024;
    scan_block_kernel<<<nsb, 256, 0, stream>>>(cnt, off, bsum, NBKT);
    scan_block_kernel<<<1, 256, 0, stream>>>(bsum, bsum, nullptr, nsb);
    fill2_kernel<<<(ET + 255) / 256, 256, 0, stream>>>(src0, dst0, et0, E0, src1, dst1, et1, E1, pos, off, bsum, ssrc);

    // ---------------- layer 0: gather + fused GEMM (stats fused) -----------
    gather_kernel<<<(NREL * ND0 * 64) / 256, 256, 0, stream>>>(
        xb, ssrc, cnt, off, bsum, 0, NREL * ND0, S0, nullptr, nullptr, nullptr, 0.f);
    {
        GemmArgs ga = {};
        for (int s = 0; s < NREL; s++)
            ga.seg[s] = { S0 + (size_t)s * ND0 * HD, W0t + (size_t)s * 65536 };
        ga.seg[5] = { xb, Wl0t };
        ga.nseg = 6; ga.fseg = -1;
        ga.bias = b0; ga.stats = st0;
        ga.Cb = h0b; ga.Cf = nullptr; ga.M = ND0; ga.N = HD;
        gemm_mfma_kernel<256, 128, 2><<<dim3(2, (ND0 + 255) / 256), 256, 0, stream>>>(ga);
    }

    // ---------------- layer 1: gather (BN+ELU fused) + fused GEMM ----------
    gather_kernel<<<(NREL * ND1 * 64) / 256, 256, 0, stream>>>(
        h0b, ssrc, cnt, off, bsum, NREL * ND0, NREL * ND1, S1, st0, g0, be0, 1.f / ND0);
    {
        GemmArgs ga = {};
        for (int s = 0; s < NREL; s++)
            ga.seg[s] = { S1 + (size_t)s * ND1 * HD, W1t + (size_t)s * 65536 };
        ga.seg[5] = { h0b, Wl1t };
        ga.nseg = 6; ga.fseg = 5; ga.fact = 1;
        ga.fst = st0; ga.fg = g0; ga.fbe = be0; ga.finv = 1.f / ND0;
        ga.bias = b1; ga.stats = st1;
        ga.Cb = h1b; ga.Cf = nullptr; ga.M = ND1; ga.N = HD;
        gemm_mfma_kernel<64, 64, 4><<<dim3(4, (ND1 + 63) / 64), 256, 0, stream>>>(ga);
    }

    // ---------------- MLP head ---------------------------------------------
    {
        GemmArgs ga = {};
        ga.seg[0] = { h1b, Wm1t };
        ga.nseg = 1; ga.fseg = 0; ga.fact = 1;
        ga.fst = st1; ga.fg = g1; ga.fbe = be1; ga.finv = 1.f / ND1;
        ga.bias = bm1; ga.stats = stm;
        ga.Cb = mb; ga.Cf = nullptr; ga.M = ND1; ga.N = HD;
        gemm_mfma_kernel<64, 64, 4><<<dim3(4, (ND1 + 63) / 64), 256, 0, stream>>>(ga);
    }
    {
        GemmArgs ga = {};
        ga.seg[0] = { mb, Wm2t };
        ga.nseg = 1; ga.fseg = 0; ga.fact = 2;
        ga.fst = stm; ga.fg = gm; ga.fbe = bem; ga.finv = 1.f / ND1;
        ga.bias = bm2; ga.stats = nullptr;
        ga.Cb = nullptr; ga.Cf = (float*)d_out; ga.M = ND1; ga.N = NOUT;
        gemm_mfma_kernel<64, 64, 4><<<dim3((NOUT + 63) / 64, (ND1 + 63) / 64), 256, 0, stream>>>(ga);
    }
}